// Round 1
// baseline (2017.503 us; speedup 1.0000x reference)
//
#include <hip/hip_runtime.h>

#define D_DIM   768
#define P_ROWS  4096
#define M_NODES 65536
#define TAU_INV 50.0f
#define MARGIN  3.5f

#define PT      64                    // patches per P1 block
#define NCHUNKS 8
#define CHUNK   (M_NODES / NCHUNKS)   // 8192 nodes per chunk
#define BN      64                    // node tile
#define BK      128                   // K slice
#define CAPMAX  256                   // candidate cap per row

#define A_STRIDE (D_DIM + 8)          // +16B pad: break 1536B-stride bank conflict
#define B_STRIDE (BK + 8)

typedef __attribute__((ext_vector_type(8))) __bf16 bf16x8;
typedef __attribute__((ext_vector_type(8))) short  short8;
typedef __attribute__((ext_vector_type(4))) float  f32x4;

__device__ __forceinline__ unsigned short f2bf(float f) {
  unsigned u = __float_as_uint(f);
  u += 0x7fffu + ((u >> 16) & 1u);            // RNE
  return (unsigned short)(u >> 16);
}
// monotone float<->uint encoding so atomicMax(uint) == float max (handles negatives)
__device__ __forceinline__ unsigned encf(float f) {
  unsigned u = __float_as_uint(f);
  return (u & 0x80000000u) ? ~u : (u | 0x80000000u);
}
__device__ __forceinline__ float decf(unsigned e) {
  unsigned u = (e & 0x80000000u) ? (e & 0x7fffffffu) : ~e;
  return __uint_as_float(u);
}

__global__ void p0_zero(int* __restrict__ cnt) {
  int i = blockIdx.x * 256 + threadIdx.x;
  if (i < P_ROWS) cnt[i] = 0;
}

// P1: bf16 MFMA scan of all sims; per-row chunk-local running max; collect
// candidate node indices with sim >= runningmax - MARGIN into global lists.
__global__ __launch_bounds__(512, 2) void p1_scan(
    const float* __restrict__ patches, const float* __restrict__ nodes,
    int* __restrict__ cnt, int* __restrict__ cand, int cap) {
  __shared__ unsigned short Atile[PT * A_STRIDE];   // ~99 KB
  __shared__ unsigned short Btile[BN * B_STRIDE];   // ~17 KB
  __shared__ unsigned thrbits[PT];

  const int tid   = threadIdx.x;
  const int ptile = blockIdx.x & (P_ROWS / PT - 1);
  const int chunk = blockIdx.x / (P_ROWS / PT);
  const int prow0 = ptile * PT;
  const int node0 = chunk * CHUNK;

  if (tid < PT) thrbits[tid] = encf(-3.0e38f);

  // stage A tile: PT x 768 fp32 -> bf16 LDS (once per block)
  #pragma unroll
  for (int i = 0; i < (PT * D_DIM / 4) / 512; ++i) {
    int v  = tid + i * 512;
    int r  = v / (D_DIM / 4);
    int c4 = v - r * (D_DIM / 4);
    float4 f = *(const float4*)(patches + (size_t)(prow0 + r) * D_DIM + c4 * 4);
    ushort4 h = { f2bf(f.x), f2bf(f.y), f2bf(f.z), f2bf(f.w) };
    *(ushort4*)(&Atile[r * A_STRIDE + c4 * 4]) = h;
  }
  __syncthreads();

  const int wid   = tid >> 6;       // 8 waves
  const int lane  = tid & 63;
  const int strip = wid >> 1;       // 4 row-strips of 16
  const int nhalf = wid & 1;        // 2 node-halves of 32
  const int l15   = lane & 15;
  const int lhi   = lane >> 4;
  const int rbase = strip * 16 + lhi * 4;   // C/D: row=(lane>>4)*4+reg, col=lane&15
  const unsigned short* Arow  = &Atile[(strip * 16 + l15) * A_STRIDE];
  const unsigned short* Brow0 = &Btile[(nhalf * 32 + l15) * B_STRIDE];
  const unsigned short* Brow1 = &Btile[(nhalf * 32 + 16 + l15) * B_STRIDE];

  for (int nt = 0; nt < CHUNK / BN; ++nt) {
    const int nodeBase = node0 + nt * BN;
    f32x4 acc0 = {0.f, 0.f, 0.f, 0.f};
    f32x4 acc1 = {0.f, 0.f, 0.f, 0.f};

    for (int ks = 0; ks < D_DIM / BK; ++ks) {
      // stage B slice: BN x BK fp32 -> bf16 LDS
      #pragma unroll
      for (int i = 0; i < (BN * BK / 4) / 512; ++i) {
        int v  = tid + i * 512;
        int r  = v >> 5;            // BK/4 = 32 float4 per row
        int c4 = v & 31;
        float4 f = *(const float4*)(nodes + (size_t)(nodeBase + r) * D_DIM + ks * BK + c4 * 4);
        ushort4 h = { f2bf(f.x), f2bf(f.y), f2bf(f.z), f2bf(f.w) };
        *(ushort4*)(&Btile[r * B_STRIDE + c4 * 4]) = h;
      }
      __syncthreads();
      #pragma unroll
      for (int kk = 0; kk < BK / 32; ++kk) {
        const int ko = kk * 32 + lhi * 8;   // A/B frag: lane&15=row/col, 8 contiguous k
        bf16x8 a  = __builtin_bit_cast(bf16x8, *(const short8*)(Arow + ks * BK + ko));
        bf16x8 b0 = __builtin_bit_cast(bf16x8, *(const short8*)(Brow0 + ko));
        bf16x8 b1 = __builtin_bit_cast(bf16x8, *(const short8*)(Brow1 + ko));
        acc0 = __builtin_amdgcn_mfma_f32_16x16x32_bf16(a, b0, acc0, 0, 0, 0);
        acc1 = __builtin_amdgcn_mfma_f32_16x16x32_bf16(a, b1, acc1, 0, 0, 0);
      }
      __syncthreads();
    }

    // ---- running row-max update + candidate collection ----
    float rm[4];
    #pragma unroll
    for (int j = 0; j < 4; ++j) rm[j] = fmaxf(acc0[j], acc1[j]);
    #pragma unroll
    for (int m = 1; m <= 8; m <<= 1) {      // reduce over the 16 lanes sharing rows
      #pragma unroll
      for (int j = 0; j < 4; ++j) rm[j] = fmaxf(rm[j], __shfl_xor(rm[j], m, 64));
    }
    if (l15 == 0) {
      #pragma unroll
      for (int j = 0; j < 4; ++j) atomicMax(&thrbits[rbase + j], encf(rm[j]));
    }
    #pragma unroll
    for (int j = 0; j < 4; ++j) {
      const float thr  = fmaxf(decf(thrbits[rbase + j]), rm[j]) - MARGIN;
      const int   prow = prow0 + rbase + j;
      const float s0 = acc0[j], s1 = acc1[j];
      if (s0 >= thr) {
        int slot = atomicAdd(&cnt[prow], 1);
        if (slot < cap) cand[prow * cap + slot] = nodeBase + nhalf * 32 + l15;
      }
      if (s1 >= thr) {
        int slot = atomicAdd(&cnt[prow], 1);
        if (slot < cap) cand[prow * cap + slot] = nodeBase + nhalf * 32 + 16 + l15;
      }
    }
  }
}

// P2: exact fp32 rescoring of candidates, softmax(tau), weighted gather.
__global__ __launch_bounds__(256) void p2_finish(
    const float* __restrict__ patches, const float* __restrict__ nodes,
    const int* __restrict__ cnt, const int* __restrict__ cand, int cap,
    float* __restrict__ out) {
  __shared__ float prow[D_DIM];
  __shared__ float simbuf[CAPMAX];
  __shared__ float wbuf[CAPMAX];
  __shared__ float red[4];
  __shared__ float mZ[2];

  const int p   = blockIdx.x;
  const int tid = threadIdx.x;
  for (int i = tid; i < D_DIM; i += 256) prow[i] = patches[(size_t)p * D_DIM + i];
  int n = cnt[p];
  if (n > cap) n = cap;
  __syncthreads();

  const int wid = tid >> 6, lane = tid & 63;
  // exact fp32 dot per candidate (one wave per candidate, round-robin)
  for (int j = wid; j < n; j += 4) {
    const float* nr = nodes + (size_t)cand[p * cap + j] * D_DIM;
    float s = 0.f;
    #pragma unroll
    for (int i = 0; i < D_DIM / 64; ++i)
      s += nr[lane + i * 64] * prow[lane + i * 64];
    #pragma unroll
    for (int m = 1; m < 64; m <<= 1) s += __shfl_xor(s, m, 64);
    if (lane == 0) simbuf[j] = s;
  }
  __syncthreads();

  // block max
  float v = (tid < n) ? simbuf[tid] : -3.0e38f;
  #pragma unroll
  for (int m = 1; m < 64; m <<= 1) v = fmaxf(v, __shfl_xor(v, m, 64));
  if (lane == 0) red[wid] = v;
  __syncthreads();
  if (tid == 0) mZ[0] = fmaxf(fmaxf(red[0], red[1]), fmaxf(red[2], red[3]));
  __syncthreads();
  const float mm = mZ[0];
  wbuf[tid] = (tid < n) ? expf((simbuf[tid] - mm) * TAU_INV) : 0.f;
  __syncthreads();
  if (tid == 0) {
    float Z = 0.f;
    for (int j = 0; j < n; ++j) Z += wbuf[j];
    mZ[1] = Z;
  }
  __syncthreads();
  const float invZ = 1.0f / mZ[1];

  // weighted gather: out[p][d] = sum_j w_j * node[idx_j][d]
  float acc[3] = {0.f, 0.f, 0.f};
  for (int j = 0; j < n; ++j) {
    const float e = wbuf[j];
    if (e < 1e-12f) continue;                 // weight < 1e-12: invisible at absmax 0.1
    const float w = e * invZ;
    const float* nr = nodes + (size_t)cand[p * cap + j] * D_DIM;
    #pragma unroll
    for (int q = 0; q < 3; ++q) acc[q] += w * nr[tid + q * 256];
  }
  #pragma unroll
  for (int q = 0; q < 3; ++q) out[(size_t)p * D_DIM + tid + q * 256] = acc[q];
}

extern "C" void kernel_launch(void* const* d_in, const int* in_sizes, int n_in,
                              void* d_out, int out_size, void* d_ws, size_t ws_size,
                              hipStream_t stream) {
  const float* patches = (const float*)d_in[0];
  const float* nodes   = (const float*)d_in[1];
  float* out = (float*)d_out;

  int* cnt  = (int*)d_ws;
  int* cand = (int*)((char*)d_ws + (size_t)P_ROWS * sizeof(int));

  int cap = CAPMAX;
  size_t hdr = (size_t)P_ROWS * sizeof(int);
  if (ws_size > hdr) {
    size_t per = (ws_size - hdr) / ((size_t)P_ROWS * sizeof(int));
    if (per < (size_t)cap) cap = (int)per;
  } else {
    cap = 1;
  }
  if (cap < 1) cap = 1;

  p0_zero<<<dim3((P_ROWS + 255) / 256), dim3(256), 0, stream>>>(cnt);
  p1_scan<<<dim3((P_ROWS / PT) * NCHUNKS), dim3(512), 0, stream>>>(patches, nodes, cnt, cand, cap);
  p2_finish<<<dim3(P_ROWS), dim3(256), 0, stream>>>(patches, nodes, cnt, cand, cap, out);
}

// Round 2
// 898.626 us; speedup vs baseline: 2.2451x; 2.2451x over previous
//
#include <hip/hip_runtime.h>

#define D_DIM   768
#define P_ROWS  4096
#define M_NODES 65536
#define TAU_INV 50.0f
#define MARGIN  3.5f

#define NCHUNKS 8
#define CHUNK   (M_NODES / NCHUNKS)   // 8192 nodes per chunk
#define CAPMAX  256                   // candidate cap per row

// ---------- fast path geometry ----------
#define PT2     128                   // patches per block (8 waves x 16 rows)
#define BN2     64                    // node tile
#define NSL     6                     // 768/128 k-slices
#define NT2     (CHUNK / BN2)         // 128 node tiles per chunk
#define ROWB    1536                  // node/patch row bytes in bf16 (768*2)

// ---------- fallback geometry (round-1 kernel, kept verbatim) ----------
#define PT      64
#define BN      64
#define BK      128
#define A_STRIDE (D_DIM + 8)
#define B_STRIDE (BK + 8)

typedef __attribute__((ext_vector_type(8))) __bf16 bf16x8;
typedef __attribute__((ext_vector_type(8))) short  short8;
typedef __attribute__((ext_vector_type(4))) float  f32x4;

__device__ __forceinline__ unsigned short f2bf(float f) {
  unsigned u = __float_as_uint(f);
  u += 0x7fffu + ((u >> 16) & 1u);            // RNE
  return (unsigned short)(u >> 16);
}
__device__ __forceinline__ unsigned encf(float f) {
  unsigned u = __float_as_uint(f);
  return (u & 0x80000000u) ? ~u : (u | 0x80000000u);
}
__device__ __forceinline__ float decf(unsigned e) {
  unsigned u = (e & 0x80000000u) ? (e & 0x7fffffffu) : ~e;
  return __uint_as_float(u);
}
__device__ __forceinline__ void gload_lds16(const void* g, void* l) {
  __builtin_amdgcn_global_load_lds(
      (const __attribute__((address_space(1))) unsigned*)g,
      (__attribute__((address_space(3))) unsigned*)l, 16, 0, 0);
}

__global__ void p0_zero(int* __restrict__ cnt) {
  int i = blockIdx.x * 256 + threadIdx.x;
  if (i < P_ROWS) cnt[i] = 0;
}

// fp32 -> bf16 bulk convert (8 elems/thread/iter, 16B stores)
__global__ void pconv(const float* __restrict__ in, unsigned short* __restrict__ out, int n8) {
  for (int i = blockIdx.x * 256 + threadIdx.x; i < n8; i += gridDim.x * 256) {
    float4 f0 = ((const float4*)in)[(size_t)i * 2];
    float4 f1 = ((const float4*)in)[(size_t)i * 2 + 1];
    short8 h;
    h[0] = (short)f2bf(f0.x); h[1] = (short)f2bf(f0.y);
    h[2] = (short)f2bf(f0.z); h[3] = (short)f2bf(f0.w);
    h[4] = (short)f2bf(f1.x); h[5] = (short)f2bf(f1.y);
    h[6] = (short)f2bf(f1.z); h[7] = (short)f2bf(f1.w);
    *(short8*)(out + (size_t)i * 8) = h;
  }
}

// ================= FAST P1: bf16 inputs, A-in-reg, gload_lds B, 1 barrier/slice =================
// grid = 256 blocks: chunk = bid & 7 (pins each chunk to one XCD), ptile = bid >> 3.
__global__ __launch_bounds__(512, 2) void p1_fast(
    const unsigned short* __restrict__ pbf, const unsigned short* __restrict__ nbf,
    int* __restrict__ cnt, int* __restrict__ cand, int cap) {
  __shared__ unsigned short Bbuf[2][BN2 * 128];   // 2 x 16 KB, linear (gload_lds dest)

  const int tid  = threadIdx.x;
  const int wid  = tid >> 6;
  const int lane = tid & 63;
  const int l15  = lane & 15;
  const int lhi  = lane >> 4;

  const int chunk = blockIdx.x & 7;
  const int ptile = blockIdx.x >> 3;
  const int prow0 = ptile * PT2;
  const int node0 = chunk * CHUNK;

  // ---- A strip -> VGPRs: wave wid owns rows prow0 + wid*16 + (0..15); lane l15 = its row
  bf16x8 a[24];
  {
    const unsigned short* ap = pbf + (size_t)(prow0 + wid * 16 + l15) * D_DIM + lhi * 8;
    #pragma unroll
    for (int t = 0; t < 24; ++t)
      a[t] = __builtin_bit_cast(bf16x8, *(const short8*)(ap + t * 32));
  }

  // ---- staging source offsets (swizzle on SOURCE; LDS dest stays linear — rule #21)
  // issue q = wid*2+i writes LDS linear [q*1024 + lane*16]; that slot holds logical
  // (r = q*4 + lhi, c = l15 ^ (r&7)) of the 64x128 bf16 slice.
  const int q0 = wid * 2, q1 = wid * 2 + 1;
  const int r0 = q0 * 4 + lhi, r1 = q1 * 4 + lhi;
  const size_t srcOff0 = (size_t)r0 * ROWB + (size_t)((l15 ^ (r0 & 7)) << 4);
  const size_t srcOff1 = (size_t)r1 * ROWB + (size_t)((l15 ^ (r1 & 7)) << 4);
  const char* nbase = (const char*)nbf + (size_t)node0 * ROWB;
  char* ldsd0[2], *ldsd1[2];
  #pragma unroll
  for (int b = 0; b < 2; ++b) {
    ldsd0[b] = (char*)&Bbuf[b][0] + q0 * 1024;
    ldsd1[b] = (char*)&Bbuf[b][0] + q1 * 1024;
  }
  // read-side swizzle constants: slot = kk*4+lhi, XOR (row&7)=(l15&7)
  int swk[4];
  #pragma unroll
  for (int kk = 0; kk < 4; ++kk) swk[kk] = (((kk * 4 + lhi) ^ (l15 & 7)) << 4);
  const int rowB = l15 * 256;

  // prologue: stage slice 0
  gload_lds16(nbase + srcOff0, ldsd0[0]);
  gload_lds16(nbase + srcOff1, ldsd1[0]);
  __syncthreads();

  int cur = 0;
  size_t ntBase = 0;                      // byte base of current nt's slice group
  float runm[4] = {-3.0e38f, -3.0e38f, -3.0e38f, -3.0e38f};

  for (int nt = 0; nt < NT2; ++nt) {
    f32x4 acc[4] = {{0,0,0,0},{0,0,0,0},{0,0,0,0},{0,0,0,0}};

    #pragma unroll
    for (int ks = 0; ks < NSL; ++ks) {
      // stage slice t+1 into buf[cur^1] (clamped to slice 0 on the very last step)
      size_t nb;
      if (ks < NSL - 1)          nb = ntBase + (size_t)(ks + 1) * 256;
      else if (nt < NT2 - 1)     nb = ntBase + (size_t)BN2 * ROWB;
      else                       nb = 0;
      gload_lds16(nbase + nb + srcOff0, ldsd0[cur ^ 1]);
      gload_lds16(nbase + nb + srcOff1, ldsd1[cur ^ 1]);

      const char* bb = (const char*)&Bbuf[cur][0] + rowB;
      #pragma unroll
      for (int kk = 0; kk < 4; ++kk) {
        bf16x8 b[4];
        #pragma unroll
        for (int g = 0; g < 4; ++g)
          b[g] = __builtin_bit_cast(bf16x8, *(const short8*)(bb + g * 4096 + swk[kk]));
        #pragma unroll
        for (int g = 0; g < 4; ++g)
          acc[g] = __builtin_amdgcn_mfma_f32_16x16x32_bf16(a[ks * 4 + kk], b[g], acc[g], 0, 0, 0);
      }
      __syncthreads();
      cur ^= 1;
    }
    ntBase += (size_t)BN2 * ROWB;

    // ---- running row-max (row lives entirely in this wave) + candidate collection
    float rm[4];
    #pragma unroll
    for (int j = 0; j < 4; ++j)
      rm[j] = fmaxf(fmaxf(acc[0][j], acc[1][j]), fmaxf(acc[2][j], acc[3][j]));
    #pragma unroll
    for (int m = 1; m <= 8; m <<= 1) {
      #pragma unroll
      for (int j = 0; j < 4; ++j) rm[j] = fmaxf(rm[j], __shfl_xor(rm[j], m, 64));
    }
    const int nodeB = node0 + nt * BN2;
    #pragma unroll
    for (int j = 0; j < 4; ++j) {
      runm[j] = fmaxf(runm[j], rm[j]);
      const float thr  = runm[j] - MARGIN;
      const int   prow = prow0 + wid * 16 + lhi * 4 + j;
      #pragma unroll
      for (int g = 0; g < 4; ++g) {
        if (acc[g][j] >= thr) {
          int slot = atomicAdd(&cnt[prow], 1);
          if (slot < cap) cand[prow * cap + slot] = nodeB + g * 16 + l15;
        }
      }
    }
  }
}

// ================= FALLBACK P1 (round-1, known-good) =================
__global__ __launch_bounds__(512, 2) void p1_scan_fb(
    const float* __restrict__ patches, const float* __restrict__ nodes,
    int* __restrict__ cnt, int* __restrict__ cand, int cap) {
  __shared__ unsigned short Atile[PT * A_STRIDE];
  __shared__ unsigned short Btile[BN * B_STRIDE];
  __shared__ unsigned thrbits[PT];

  const int tid   = threadIdx.x;
  const int ptile = blockIdx.x & (P_ROWS / PT - 1);
  const int chunk = blockIdx.x / (P_ROWS / PT);
  const int prow0 = ptile * PT;
  const int node0 = chunk * CHUNK;

  if (tid < PT) thrbits[tid] = encf(-3.0e38f);

  #pragma unroll
  for (int i = 0; i < (PT * D_DIM / 4) / 512; ++i) {
    int v  = tid + i * 512;
    int r  = v / (D_DIM / 4);
    int c4 = v - r * (D_DIM / 4);
    float4 f = *(const float4*)(patches + (size_t)(prow0 + r) * D_DIM + c4 * 4);
    ushort4 h = { f2bf(f.x), f2bf(f.y), f2bf(f.z), f2bf(f.w) };
    *(ushort4*)(&Atile[r * A_STRIDE + c4 * 4]) = h;
  }
  __syncthreads();

  const int wid   = tid >> 6;
  const int lane  = tid & 63;
  const int strip = wid >> 1;
  const int nhalf = wid & 1;
  const int l15   = lane & 15;
  const int lhi   = lane >> 4;
  const int rbase = strip * 16 + lhi * 4;
  const unsigned short* Arow  = &Atile[(strip * 16 + l15) * A_STRIDE];
  const unsigned short* Brow0 = &Btile[(nhalf * 32 + l15) * B_STRIDE];
  const unsigned short* Brow1 = &Btile[(nhalf * 32 + 16 + l15) * B_STRIDE];

  for (int nt = 0; nt < CHUNK / BN; ++nt) {
    const int nodeBase = node0 + nt * BN;
    f32x4 acc0 = {0.f, 0.f, 0.f, 0.f};
    f32x4 acc1 = {0.f, 0.f, 0.f, 0.f};

    for (int ks = 0; ks < D_DIM / BK; ++ks) {
      #pragma unroll
      for (int i = 0; i < (BN * BK / 4) / 512; ++i) {
        int v  = tid + i * 512;
        int r  = v >> 5;
        int c4 = v & 31;
        float4 f = *(const float4*)(nodes + (size_t)(nodeBase + r) * D_DIM + ks * BK + c4 * 4);
        ushort4 h = { f2bf(f.x), f2bf(f.y), f2bf(f.z), f2bf(f.w) };
        *(ushort4*)(&Btile[r * B_STRIDE + c4 * 4]) = h;
      }
      __syncthreads();
      #pragma unroll
      for (int kk = 0; kk < BK / 32; ++kk) {
        const int ko = kk * 32 + lhi * 8;
        bf16x8 va = __builtin_bit_cast(bf16x8, *(const short8*)(Arow + ks * BK + ko));
        bf16x8 b0 = __builtin_bit_cast(bf16x8, *(const short8*)(Brow0 + ko));
        bf16x8 b1 = __builtin_bit_cast(bf16x8, *(const short8*)(Brow1 + ko));
        acc0 = __builtin_amdgcn_mfma_f32_16x16x32_bf16(va, b0, acc0, 0, 0, 0);
        acc1 = __builtin_amdgcn_mfma_f32_16x16x32_bf16(va, b1, acc1, 0, 0, 0);
      }
      __syncthreads();
    }

    float rm[4];
    #pragma unroll
    for (int j = 0; j < 4; ++j) rm[j] = fmaxf(acc0[j], acc1[j]);
    #pragma unroll
    for (int m = 1; m <= 8; m <<= 1) {
      #pragma unroll
      for (int j = 0; j < 4; ++j) rm[j] = fmaxf(rm[j], __shfl_xor(rm[j], m, 64));
    }
    if (l15 == 0) {
      #pragma unroll
      for (int j = 0; j < 4; ++j) atomicMax(&thrbits[rbase + j], encf(rm[j]));
    }
    #pragma unroll
    for (int j = 0; j < 4; ++j) {
      const float thr  = fmaxf(decf(thrbits[rbase + j]), rm[j]) - MARGIN;
      const int   prow = prow0 + rbase + j;
      if (acc0[j] >= thr) {
        int slot = atomicAdd(&cnt[prow], 1);
        if (slot < cap) cand[prow * cap + slot] = nodeBase + nhalf * 32 + l15;
      }
      if (acc1[j] >= thr) {
        int slot = atomicAdd(&cnt[prow], 1);
        if (slot < cap) cand[prow * cap + slot] = nodeBase + nhalf * 32 + 16 + l15;
      }
    }
  }
}

// ================= P2: exact fp32 rescore + softmax + gather =================
__global__ __launch_bounds__(256) void p2_finish(
    const float* __restrict__ patches, const float* __restrict__ nodes,
    const int* __restrict__ cnt, const int* __restrict__ cand, int cap,
    float* __restrict__ out) {
  __shared__ float prow[D_DIM];
  __shared__ float simbuf[CAPMAX];
  __shared__ float wbuf[CAPMAX];
  __shared__ float red[4];
  __shared__ float mZ[2];

  const int p   = blockIdx.x;
  const int tid = threadIdx.x;
  for (int i = tid; i < D_DIM; i += 256) prow[i] = patches[(size_t)p * D_DIM + i];
  int n = cnt[p];
  if (n > cap) n = cap;
  __syncthreads();

  const int wid = tid >> 6, lane = tid & 63;
  for (int j = wid; j < n; j += 4) {
    const float* nr = nodes + (size_t)cand[p * cap + j] * D_DIM;
    float s = 0.f;
    #pragma unroll
    for (int i = 0; i < D_DIM / 64; ++i)
      s += nr[lane + i * 64] * prow[lane + i * 64];
    #pragma unroll
    for (int m = 1; m < 64; m <<= 1) s += __shfl_xor(s, m, 64);
    if (lane == 0) simbuf[j] = s;
  }
  __syncthreads();

  float v = (tid < n) ? simbuf[tid] : -3.0e38f;
  #pragma unroll
  for (int m = 1; m < 64; m <<= 1) v = fmaxf(v, __shfl_xor(v, m, 64));
  if (lane == 0) red[wid] = v;
  __syncthreads();
  if (tid == 0) mZ[0] = fmaxf(fmaxf(red[0], red[1]), fmaxf(red[2], red[3]));
  __syncthreads();
  const float mm = mZ[0];
  wbuf[tid] = (tid < n) ? expf((simbuf[tid] - mm) * TAU_INV) : 0.f;
  __syncthreads();
  if (tid == 0) {
    float Z = 0.f;
    for (int j = 0; j < n; ++j) Z += wbuf[j];
    mZ[1] = Z;
  }
  __syncthreads();
  const float invZ = 1.0f / mZ[1];

  float acc[3] = {0.f, 0.f, 0.f};
  for (int j = 0; j < n; ++j) {
    const float e = wbuf[j];
    if (e < 1e-12f) continue;
    const float w = e * invZ;
    const float* nr = nodes + (size_t)cand[p * cap + j] * D_DIM;
    #pragma unroll
    for (int q = 0; q < 3; ++q) acc[q] += w * nr[tid + q * 256];
  }
  #pragma unroll
  for (int q = 0; q < 3; ++q) out[(size_t)p * D_DIM + tid + q * 256] = acc[q];
}

extern "C" void kernel_launch(void* const* d_in, const int* in_sizes, int n_in,
                              void* d_out, int out_size, void* d_ws, size_t ws_size,
                              hipStream_t stream) {
  const float* patches = (const float*)d_in[0];
  const float* nodes   = (const float*)d_in[1];
  float* out = (float*)d_out;

  const size_t off_cand = 16384;                          // cnt: 4096*4
  const size_t off_pbf  = off_cand + (size_t)P_ROWS * CAPMAX * 4;
  const size_t off_nbf  = off_pbf + (size_t)P_ROWS * D_DIM * 2;
  const size_t need     = off_nbf + (size_t)M_NODES * D_DIM * 2;

  int* cnt  = (int*)d_ws;
  int* cand = (int*)((char*)d_ws + off_cand);

  p0_zero<<<dim3((P_ROWS + 255) / 256), dim3(256), 0, stream>>>(cnt);

  if (ws_size >= need) {
    unsigned short* pbf = (unsigned short*)((char*)d_ws + off_pbf);
    unsigned short* nbf = (unsigned short*)((char*)d_ws + off_nbf);
    pconv<<<dim3(1024), dim3(256), 0, stream>>>(patches, pbf, P_ROWS * D_DIM / 8);
    pconv<<<dim3(2048), dim3(256), 0, stream>>>(nodes,   nbf, M_NODES * D_DIM / 8);
    p1_fast<<<dim3((P_ROWS / PT2) * NCHUNKS), dim3(512), 0, stream>>>(pbf, nbf, cnt, cand, CAPMAX);
    p2_finish<<<dim3(P_ROWS), dim3(256), 0, stream>>>(patches, nodes, cnt, cand, CAPMAX, out);
  } else {
    int cap = CAPMAX;
    size_t hdr = (size_t)P_ROWS * sizeof(int);
    if (ws_size > hdr) {
      size_t per = (ws_size - hdr) / ((size_t)P_ROWS * sizeof(int));
      if (per < (size_t)cap) cap = (int)per;
    } else cap = 1;
    if (cap < 1) cap = 1;
    p1_scan_fb<<<dim3((P_ROWS / PT) * NCHUNKS), dim3(512), 0, stream>>>(patches, nodes, cnt, cand, cap);
    p2_finish<<<dim3(P_ROWS), dim3(256), 0, stream>>>(patches, nodes, cnt, cand, cap, out);
  }
}